// Round 12
// baseline (151.574 us; speedup 1.0000x reference)
//
#include <hip/hip_runtime.h>
#include <cstdint>

typedef float  f32x4  __attribute__((ext_vector_type(4)));
typedef short  short8 __attribute__((ext_vector_type(8)));
typedef _Float16 half4 __attribute__((ext_vector_type(4)));

// ---------- helpers ----------
__device__ __forceinline__ unsigned short f2bf(float f) {
    unsigned u = __builtin_bit_cast(unsigned, f);
    u += 0x7FFFu + ((u >> 16) & 1u);   // RNE
    return (unsigned short)(u >> 16);
}

// ---------- kernel 1: weights fp32 -> bf16 (3 x 256 x 256) ----------
__global__ void wconv_kernel(const float* __restrict__ wq,
                             const float* __restrict__ wk,
                             const float* __restrict__ wv,
                             unsigned short* __restrict__ Wb) {
    int p = blockIdx.x >> 8;                       // 0..2
    int i = ((blockIdx.x & 255) << 8) + threadIdx.x; // 0..65535
    const float* src = (p == 0) ? wq : ((p == 1) ? wk : wv);
    Wb[(p << 16) + i] = f2bf(src[i]);
}

// ---------- kernel 2: build X0 [B][S][256] bf16 ----------
__global__ void build_x0_kernel(const float* __restrict__ x,
                                unsigned short* __restrict__ X0) {
    __shared__ float tile[32][33];
    int b  = blockIdx.z;
    int ct = blockIdx.y;     // 0..7  (32 channels each)
    int st = blockIdx.x;     // 0..31 (32 s each)
    int tid = threadIdx.x;
    int lo = tid & 31, hi = tid >> 5;   // 8 rows per pass

    if (ct < 7) {
        #pragma unroll
        for (int r = 0; r < 4; ++r) {
            int c = hi + 8 * r;
            tile[c][lo] = x[((b * 224 + ct * 32 + c) << 10) + st * 32 + lo];
        }
        __syncthreads();
        #pragma unroll
        for (int r = 0; r < 4; ++r) {
            int s_loc = hi + 8 * r;
            X0[(((b << 10) + st * 32 + s_loc) << 8) + ct * 32 + lo] = f2bf(tile[lo][s_loc]);
        }
    } else {
        #pragma unroll
        for (int r = 0; r < 4; ++r) {
            int s_loc = hi + 8 * r;
            int s = st * 32 + s_loc;
            int h = s >> 5, w = s & 31;
            int ch = lo;  // 0..31 -> pe channel
            int i = (ch < 16) ? (ch * 32 + h) : ((ch - 16) * 32 + w);
            int l = i >> 4, e = i & 15;
            float val = 0.f;
            if (l > 0) {
                float ang = (float)l * powf(10000.f, -(float)(e >> 1) * 0.125f);
                val = (e & 1) ? cosf(ang) : sinf(ang);
            }
            X0[(((b << 10) + s) << 8) + 224 + ch] = f2bf(val);
        }
    }
}

// ---------- kernel 3: QKV projection, LDS-staged ----------
__global__ __launch_bounds__(256) void proj_kernel(
        const unsigned short* __restrict__ X0,
        const unsigned short* __restrict__ Wb,
        const float* __restrict__ bq, const float* __restrict__ bk,
        const float* __restrict__ bv,
        unsigned short* __restrict__ Q, unsigned short* __restrict__ K,
        _Float16* __restrict__ V) {
    __shared__ __align__(16) char Xlds[32768];   // 64 s-rows x 512B
    __shared__ __align__(16) char Wlds[32768];   // 64 o-rows x 512B

    int pb = blockIdx.z; int proj = pb >> 5; int b = pb & 31;
    int tid = threadIdx.x; int w = tid >> 6; int l = tid & 63;
    int g = l >> 4, c = l & 15;
    int sb = blockIdx.x * 64;           // s-tile base
    int o0 = blockIdx.y * 64;           // o-tile base
    const unsigned short* Wp = Wb + (proj << 16);
    const float* bias = (proj == 0) ? bq : ((proj == 1) ? bk : bv);

    // ---- stage X0 tile: 2048 16B chunks, coalesced, swizzled ----
    const unsigned short* Xg = &X0[((b << 10) + sb) << 8];
    #pragma unroll
    for (int p = 0; p < 8; ++p) {
        int ch = p * 256 + tid;
        int row = ch >> 5, cc = ch & 31;
        short8 v = *(const short8*)&Xg[(row << 8) + cc * 8];
        *(short8*)&Xlds[((ch & ~31) | (cc ^ (row & 7))) << 4] = v;
    }
    // ---- stage W tile: 2048 16B chunks ----
    const unsigned short* Wg = &Wp[o0 << 8];
    #pragma unroll
    for (int p = 0; p < 8; ++p) {
        int ch = p * 256 + tid;
        int row = ch >> 5, cc = ch & 31;
        short8 v = *(const short8*)&Wg[(row << 8) + cc * 8];
        *(short8*)&Wlds[((ch & ~31) | (cc ^ (row & 7))) << 4] = v;
    }
    __syncthreads();

    // ---- A fragments (this wave's 16 s-rows) into registers ----
    int s0 = sb + w * 16;
    const char* abase = &Xlds[(w * 16 + c) * 512];
    short8 af[8];
    #pragma unroll
    for (int kk = 0; kk < 8; ++kk)
        af[kk] = *(const short8*)&abase[((kk * 4 + g) ^ (c & 7)) << 4];

    f32x4 acc[4];
    #pragma unroll
    for (int ot = 0; ot < 4; ++ot) acc[ot] = (f32x4){0.f, 0.f, 0.f, 0.f};

    __builtin_amdgcn_s_setprio(1);
    #pragma unroll
    for (int ot = 0; ot < 4; ++ot) {
        const char* bbase = &Wlds[(ot * 16 + c) * 512];
        #pragma unroll
        for (int kk = 0; kk < 8; ++kk) {
            short8 bfr = *(const short8*)&bbase[((kk * 4 + g) ^ (c & 7)) << 4];
            acc[ot] = __builtin_amdgcn_mfma_f32_16x16x32_bf16(af[kk], bfr, acc[ot], 0, 0, 0);
        }
    }
    __builtin_amdgcn_s_setprio(0);

    #pragma unroll
    for (int ot = 0; ot < 4; ++ot) {
        int o = o0 + ot * 16 + c;
        float bb = bias[o];
        if (proj < 2) {
            unsigned short* dst = (proj == 0) ? Q : K;
            #pragma unroll
            for (int r = 0; r < 4; ++r) {
                float v = fmaxf(acc[ot][r] + bb, 0.f);
                int s = s0 + 4 * g + r;
                dst[(((b << 10) + s) << 8) + o] = f2bf(v);
            }
        } else {
            half4 hv;
            #pragma unroll
            for (int r = 0; r < 4; ++r)
                hv[r] = (_Float16)fmaxf(acc[ot][r] + bb, 0.f);
            *(half4*)&V[(((b << 8) + o) << 10) + s0 + 4 * g] = hv;
        }
    }
}

// ---------- kernel 4: causal attention, balanced pair-in-block ----------
// 512 blocks x 256 threads. Block = (batch XCD-grouped, j in 0..15):
// processes 32-row q-tile j, THEN q-tile 31-j  ->  exactly 33 t32-tiles
// per block (perfectly equal work, no causal tail).
// 4 waves = (row-half rh) x (v-half vh): each wave 16 q-rows x 128 v.
// Single-buffered LDS 32KB (K 16KB swz row&7; V 16KB rows 64B, 16B chunk
// ci ^ ((v>>1)&3) = conflict-free b64 reads)  ->  4 blocks/CU = 4 waves/SIMD.
__global__ __launch_bounds__(256, 4) void attn_kernel(
        const unsigned short* __restrict__ Q,
        const unsigned short* __restrict__ K,
        const _Float16* __restrict__ V,
        float* __restrict__ out) {
    __shared__ __align__(16) char Klds[16384];   // 32 t-rows x 512B
    __shared__ __align__(16) char Vlds[16384];   // 256 v-rows x 64B

    int bid = blockIdx.x;
    int xcd = bid & 7;
    int j   = (bid >> 3) & 15;
    int bhi = bid >> 7;                  // 0..3
    int b   = (bhi << 3) | xcd;          // batches grouped per XCD

    int tid = threadIdx.x; int w = tid >> 6; int l = tid & 63;
    int g = l >> 4, c = l & 15;
    int rh = w >> 1, vh = w & 1;

    const unsigned short* Kb_ = &K[(size_t)b << 18];
    const _Float16*       Vb_ = &V[(size_t)b << 18];

    #pragma unroll 1
    for (int ph = 0; ph < 2; ++ph) {
        int jt = ph ? (31 - j) : j;      // 32-row q-tile index
        int s0 = (jt << 5) + (rh << 4);  // this wave's 16 q-rows

        // ---- Q fragments for this phase ----
        short8 qf[8];
        #pragma unroll
        for (int kk = 0; kk < 8; ++kk)
            qf[kk] = *(const short8*)&Q[(((b << 10) + s0 + c) << 8) + kk * 32 + g * 8];

        float m = -1e30f, lsum = 0.f;    // lsum: per-lane partial
        f32x4 acc[8];
        #pragma unroll
        for (int i = 0; i < 8; ++i) acc[i] = (f32x4){0.f, 0.f, 0.f, 0.f};

        int ntile = jt + 1;
        #pragma unroll 1
        for (int t = 0; t < ntile; ++t) {
            int t0 = t << 5;
            // ---- stage K tile: 1024 chunks + V tile: 1024 chunks ----
            #pragma unroll
            for (int j4 = 0; j4 < 4; ++j4) {
                int q = (j4 << 8) + tid;             // 0..1023
                int trow = q >> 5, cc = q & 31;
                int cl = cc ^ (trow & 7);
                __builtin_amdgcn_global_load_lds(
                    (const unsigned int*)&Kb_[((t0 + trow) << 8) + cl * 8],
                    (unsigned int*)(Klds + q * 16), 16, 0, 0);
            }
            #pragma unroll
            for (int j4 = 0; j4 < 4; ++j4) {
                int q = (j4 << 8) + tid;             // 0..1023
                int v = q >> 2, cpos = q & 3;
                int ci = cpos ^ ((v >> 1) & 3);
                __builtin_amdgcn_global_load_lds(
                    (const unsigned int*)&Vb_[(v << 10) + t0 + ci * 8],
                    (unsigned int*)(Vlds + q * 16), 16, 0, 0);
            }
            asm volatile("s_waitcnt vmcnt(0)\n\ts_barrier" ::: "memory");

            #pragma unroll
            for (int sub = 0; sub < 2; ++sub) {
                bool dmask = (t == jt) && (sub == rh);      // diagonal 16x16
                if ((t == jt) && rh == 0 && sub == 1) break; // fully above diag
                int toff = sub << 4;
                // ---- QK^T from LDS (16x16x32, 2 chains) ----
                f32x4 sc0 = {0.f,0.f,0.f,0.f}, sc1 = {0.f,0.f,0.f,0.f};
                const char* kbase = &Klds[(toff + c) * 512];
                __builtin_amdgcn_s_setprio(1);
                #pragma unroll
                for (int kk = 0; kk < 8; kk += 2) {
                    short8 a0 = *(const short8*)&kbase[(((kk * 4 + g)       ^ (c & 7)) << 4)];
                    short8 a1 = *(const short8*)&kbase[((((kk + 1) * 4 + g) ^ (c & 7)) << 4)];
                    sc0 = __builtin_amdgcn_mfma_f32_16x16x32_bf16(a0, qf[kk], sc0, 0, 0, 0);
                    sc1 = __builtin_amdgcn_mfma_f32_16x16x32_bf16(a1, qf[kk + 1], sc1, 0, 0, 0);
                }
                __builtin_amdgcn_s_setprio(0);
                // ---- V fragments (conflict-free swizzle) ----
                half4 vf[8];
                #pragma unroll
                for (int vt = 0; vt < 8; ++vt) {
                    int v = (vh << 7) + vt * 16 + c;
                    int cpos = ((sub << 1) + (g >> 1)) ^ ((v >> 1) & 3);
                    vf[vt] = *(const half4*)&Vlds[(v << 6) + (cpos << 4) + (g & 1) * 8];
                }
                // ---- scale + diagonal mask ----
                float sv[4];
                #pragma unroll
                for (int r = 0; r < 4; ++r) sv[r] = (sc0[r] + sc1[r]) * 0.0625f;
                if (dmask) {
                    #pragma unroll
                    for (int r = 0; r < 4; ++r)
                        if (4 * g + r > c) sv[r] = -1e30f;
                }
                // ---- softmax: shuffle-free fast path ----
                float tm = fmaxf(fmaxf(sv[0], sv[1]), fmaxf(sv[2], sv[3]));
                if (!__all((int)(tm <= m + 8.f))) {          // rare slow path
                    float tr = fmaxf(tm, __shfl_xor(tm, 16));
                    tr = fmaxf(tr, __shfl_xor(tr, 32));
                    float mnew = fmaxf(m, tr);
                    float alpha = __expf(m - mnew);
                    m = mnew;
                    lsum *= alpha;
                    #pragma unroll
                    for (int i = 0; i < 8; ++i) acc[i] *= alpha;
                }
                float p[4];
                #pragma unroll
                for (int r = 0; r < 4; ++r) { p[r] = __expf(sv[r] - m); lsum += p[r]; }
                half4 pb;
                #pragma unroll
                for (int r = 0; r < 4; ++r) pb[r] = (_Float16)p[r];
                // ---- PV (16x16x16 f16) ----
                __builtin_amdgcn_s_setprio(1);
                #pragma unroll
                for (int vt = 0; vt < 8; ++vt)
                    acc[vt] = __builtin_amdgcn_mfma_f32_16x16x16f16(vf[vt], pb, acc[vt], 0, 0, 0);
                __builtin_amdgcn_s_setprio(0);
            }
            __syncthreads();     // all waves done reading before next stage
        }

        // ---- epilogue: row-sum of lsum, normalize, write ----
        lsum += __shfl_xor(lsum, 16);
        lsum += __shfl_xor(lsum, 32);
        float rl = 1.f / lsum;
        #pragma unroll
        for (int vt = 0; vt < 8; ++vt) {
            #pragma unroll
            for (int r = 0; r < 4; ++r)
                out[(((b << 8) + (vh << 7) + vt * 16 + 4 * g + r) << 10) + s0 + c]
                    = acc[vt][r] * rl;
        }
    }
}

// ---------- launcher ----------
extern "C" void kernel_launch(void* const* d_in, const int* in_sizes, int n_in,
                              void* d_out, int out_size, void* d_ws, size_t ws_size,
                              hipStream_t stream) {
    const float* x  = (const float*)d_in[0];
    const float* wq = (const float*)d_in[1];
    const float* bq = (const float*)d_in[2];
    const float* wk = (const float*)d_in[3];
    const float* bk = (const float*)d_in[4];
    const float* wv = (const float*)d_in[5];
    const float* bv = (const float*)d_in[6];
    float* out = (float*)d_out;

    char* ws = (char*)d_ws;
    unsigned short* Wb = (unsigned short*)ws;                       // 393,216 B
    unsigned short* X0 = (unsigned short*)(ws + 393216);            // 16,777,216 B
    unsigned short* Qb = (unsigned short*)(ws + 393216 + 16777216);
    unsigned short* Kb = (unsigned short*)(ws + 393216 + 2 * 16777216);
    _Float16*       Vb = (_Float16*)     (ws + 393216 + 3 * 16777216);

    wconv_kernel<<<768, 256, 0, stream>>>(wq, wk, wv, Wb);
    build_x0_kernel<<<dim3(32, 8, 32), 256, 0, stream>>>(x, X0);
    proj_kernel<<<dim3(16, 4, 96), 256, 0, stream>>>(X0, Wb, bq, bk, bv, Qb, Kb, Vb);
    attn_kernel<<<512, 256, 0, stream>>>(Qb, Kb, Vb, out);
}

// Round 13
// 117.031 us; speedup vs baseline: 1.2952x; 1.2952x over previous
//
#include <hip/hip_runtime.h>
#include <cstdint>

typedef float  f32x4  __attribute__((ext_vector_type(4)));
typedef short  short8 __attribute__((ext_vector_type(8)));
typedef _Float16 half4 __attribute__((ext_vector_type(4)));
typedef _Float16 half8 __attribute__((ext_vector_type(8)));

// ---------- helpers ----------
__device__ __forceinline__ unsigned short f2bf(float f) {
    unsigned u = __builtin_bit_cast(unsigned, f);
    u += 0x7FFFu + ((u >> 16) & 1u);   // RNE
    return (unsigned short)(u >> 16);
}

// ---------- kernel 1: weights fp32 -> bf16 (3 x 256 x 256) ----------
__global__ void wconv_kernel(const float* __restrict__ wq,
                             const float* __restrict__ wk,
                             const float* __restrict__ wv,
                             unsigned short* __restrict__ Wb) {
    int p = blockIdx.x >> 8;                       // 0..2
    int i = ((blockIdx.x & 255) << 8) + threadIdx.x; // 0..65535
    const float* src = (p == 0) ? wq : ((p == 1) ? wk : wv);
    Wb[(p << 16) + i] = f2bf(src[i]);
}

// ---------- kernel 2: build X0 [B][S][256] bf16 ----------
__global__ void build_x0_kernel(const float* __restrict__ x,
                                unsigned short* __restrict__ X0) {
    __shared__ float tile[32][33];
    int b  = blockIdx.z;
    int ct = blockIdx.y;     // 0..7  (32 channels each)
    int st = blockIdx.x;     // 0..31 (32 s each)
    int tid = threadIdx.x;
    int lo = tid & 31, hi = tid >> 5;   // 8 rows per pass

    if (ct < 7) {
        #pragma unroll
        for (int r = 0; r < 4; ++r) {
            int c = hi + 8 * r;
            tile[c][lo] = x[((b * 224 + ct * 32 + c) << 10) + st * 32 + lo];
        }
        __syncthreads();
        #pragma unroll
        for (int r = 0; r < 4; ++r) {
            int s_loc = hi + 8 * r;
            X0[(((b << 10) + st * 32 + s_loc) << 8) + ct * 32 + lo] = f2bf(tile[lo][s_loc]);
        }
    } else {
        #pragma unroll
        for (int r = 0; r < 4; ++r) {
            int s_loc = hi + 8 * r;
            int s = st * 32 + s_loc;
            int h = s >> 5, w = s & 31;
            int ch = lo;  // 0..31 -> pe channel
            int i = (ch < 16) ? (ch * 32 + h) : ((ch - 16) * 32 + w);
            int l = i >> 4, e = i & 15;
            float val = 0.f;
            if (l > 0) {
                float ang = (float)l * powf(10000.f, -(float)(e >> 1) * 0.125f);
                val = (e & 1) ? cosf(ang) : sinf(ang);
            }
            X0[(((b << 10) + s) << 8) + 224 + ch] = f2bf(val);
        }
    }
}

// ---------- kernel 3: QKV projection, LDS-staged ----------
// V global layout (consumed by attn): per (b, v, 32-t tile) 32 f16 stored
// as slot = g*8 + hi*4 + j  where t_in_tile = hi*16 + 4g + j.
__global__ __launch_bounds__(256) void proj_kernel(
        const unsigned short* __restrict__ X0,
        const unsigned short* __restrict__ Wb,
        const float* __restrict__ bq, const float* __restrict__ bk,
        const float* __restrict__ bv,
        unsigned short* __restrict__ Q, unsigned short* __restrict__ K,
        _Float16* __restrict__ V) {
    __shared__ __align__(16) char Xlds[32768];   // 64 s-rows x 512B
    __shared__ __align__(16) char Wlds[32768];   // 64 o-rows x 512B

    int pb = blockIdx.z; int proj = pb >> 5; int b = pb & 31;
    int tid = threadIdx.x; int w = tid >> 6; int l = tid & 63;
    int g = l >> 4, c = l & 15;
    int sb = blockIdx.x * 64;           // s-tile base
    int o0 = blockIdx.y * 64;           // o-tile base
    const unsigned short* Wp = Wb + (proj << 16);
    const float* bias = (proj == 0) ? bq : ((proj == 1) ? bk : bv);

    // ---- stage X0 tile: 2048 16B chunks, coalesced, swizzled ----
    const unsigned short* Xg = &X0[((b << 10) + sb) << 8];
    #pragma unroll
    for (int p = 0; p < 8; ++p) {
        int ch = p * 256 + tid;
        int row = ch >> 5, cc = ch & 31;
        short8 v = *(const short8*)&Xg[(row << 8) + cc * 8];
        *(short8*)&Xlds[((ch & ~31) | (cc ^ (row & 7))) << 4] = v;
    }
    // ---- stage W tile: 2048 16B chunks ----
    const unsigned short* Wg = &Wp[o0 << 8];
    #pragma unroll
    for (int p = 0; p < 8; ++p) {
        int ch = p * 256 + tid;
        int row = ch >> 5, cc = ch & 31;
        short8 v = *(const short8*)&Wg[(row << 8) + cc * 8];
        *(short8*)&Wlds[((ch & ~31) | (cc ^ (row & 7))) << 4] = v;
    }
    __syncthreads();

    // ---- A fragments (this wave's 16 s-rows) into registers ----
    int s0 = sb + w * 16;
    const char* abase = &Xlds[(w * 16 + c) * 512];
    short8 af[8];
    #pragma unroll
    for (int kk = 0; kk < 8; ++kk)
        af[kk] = *(const short8*)&abase[((kk * 4 + g) ^ (c & 7)) << 4];

    f32x4 acc[4];
    #pragma unroll
    for (int ot = 0; ot < 4; ++ot) acc[ot] = (f32x4){0.f, 0.f, 0.f, 0.f};

    __builtin_amdgcn_s_setprio(1);
    #pragma unroll
    for (int ot = 0; ot < 4; ++ot) {
        const char* bbase = &Wlds[(ot * 16 + c) * 512];
        #pragma unroll
        for (int kk = 0; kk < 8; ++kk) {
            short8 bfr = *(const short8*)&bbase[((kk * 4 + g) ^ (c & 7)) << 4];
            acc[ot] = __builtin_amdgcn_mfma_f32_16x16x32_bf16(af[kk], bfr, acc[ot], 0, 0, 0);
        }
    }
    __builtin_amdgcn_s_setprio(0);

    #pragma unroll
    for (int ot = 0; ot < 4; ++ot) {
        int o = o0 + ot * 16 + c;
        float bb = bias[o];
        if (proj < 2) {
            unsigned short* dst = (proj == 0) ? Q : K;
            #pragma unroll
            for (int r = 0; r < 4; ++r) {
                float v = fmaxf(acc[ot][r] + bb, 0.f);
                int s = s0 + 4 * g + r;
                dst[(((b << 10) + s) << 8) + o] = f2bf(v);
            }
        } else {
            half4 hv;
            #pragma unroll
            for (int r = 0; r < 4; ++r)
                hv[r] = (_Float16)fmaxf(acc[ot][r] + bb, 0.f);
            int hi = (s0 >> 4) & 1;
            *(half4*)&V[(((b << 8) + o) << 10) + ((s0 >> 5) << 5) + (g << 3) + (hi << 2)] = hv;
        }
    }
}

// ---------- kernel 4: causal attention (R10 skeleton + cf V path) ----------
// 512 blocks x 256 threads (4 waves x 16 q-rows = 64-row q-tile).
// t-tile = 32; K (16KB, XOR row&7) + V (16KB, chunk p(v,g)=4v+(g^((v>>1)&3)))
// double-buffered (64KB). Staged via global_load_lds (pre-swizzled source).
// Pipeline: [vmcnt(0)+s_barrier] -> stage(t+1) -> compute(t).
// V fragments: ONE conflict-free b128 per (vt, tile) serving both subs.
// Softmax: per-lane partial lsum + defer-max fast path (no steady shuffles).
__global__ __launch_bounds__(256, 2) void attn_kernel(
        const unsigned short* __restrict__ Q,
        const unsigned short* __restrict__ K,
        const _Float16* __restrict__ V,
        float* __restrict__ out) {
    __shared__ __align__(16) char Klds[2][16384];   // 32 t-rows x 512B
    __shared__ __align__(16) char Vlds[2][16384];   // 1024 chunks x 16B

    int bid = blockIdx.x;
    int xcd  = bid & 7;
    int qv   = (bid >> 3) & 7;
    int bhi  = (bid >> 6) & 3;
    int hf   = bid >> 8;
    int b  = (bhi << 3) | xcd;
    int qt = hf ? qv : (15 - qv);       // 0..15, 64-row q-tile

    int tid = threadIdx.x; int w = tid >> 6; int l = tid & 63;
    int g = l >> 4, c = l & 15;
    int s0 = (qt << 6) + (w << 4);      // this wave's 16 q-rows

    // ---- Q fragments ----
    short8 qf[8];
    #pragma unroll
    for (int kk = 0; kk < 8; ++kk)
        qf[kk] = *(const short8*)&Q[(((b << 10) + s0 + c) << 8) + kk * 32 + g * 8];

    float m = -1e30f, lsum = 0.f;       // lsum: per-lane partial
    f32x4 acc[16];
    #pragma unroll
    for (int i = 0; i < 16; ++i) acc[i] = (f32x4){0.f, 0.f, 0.f, 0.f};

    const unsigned short* Kb_ = &K[(size_t)b << 18];
    const _Float16*       Vb_ = &V[(size_t)b << 18];

    int nt = 2 * qt + 2;                // 32-wide t-tiles
    int dt = 2 * qt + (w >> 1);         // this wave's diagonal t-tile

    // stage tile t into buffer bufi: 256 threads x (4 K + 4 V) chunks
    auto stage = [&](int t, int bufi) {
        int t0 = t << 5;
        #pragma unroll
        for (int j = 0; j < 4; ++j) {
            int ch = (j << 8) + tid;            // 0..1023
            int trow = ch >> 5;
            int cl = (ch & 31) ^ (trow & 7);
            __builtin_amdgcn_global_load_lds(
                (const unsigned int*)&Kb_[((t0 + trow) << 8) + cl * 8],
                (unsigned int*)(Klds[bufi] + ((j << 8) + (w << 6)) * 16), 16, 0, 0);
        }
        #pragma unroll
        for (int j = 0; j < 4; ++j) {
            int ch = (j << 8) + tid;            // 0..1023
            int v = ch >> 2;
            int gq = (ch & 3) ^ ((v >> 1) & 3);
            __builtin_amdgcn_global_load_lds(
                (const unsigned int*)&Vb_[(v << 10) + (t << 5) + gq * 8],
                (unsigned int*)(Vlds[bufi] + ((j << 8) + (w << 6)) * 16), 16, 0, 0);
        }
    };

    stage(0, 0);

    for (int t = 0; t < nt; ++t) {
        asm volatile("s_waitcnt vmcnt(0)\n\ts_barrier" ::: "memory");
        if (t + 1 < nt) stage(t + 1, (t + 1) & 1);   // overlap with compute(t)
        if (t > dt) continue;                        // done; keep barrier cadence

        const char* Kl = Klds[t & 1];
        const char* Vl = Vlds[t & 1];
        // ---- V fragments: one conflict-free b128 per vt (both subs) ----
        half8 vread[16];
        #pragma unroll
        for (int vt = 0; vt < 16; ++vt) {
            int pos = (vt << 6) + (c << 2) + (g ^ ((c >> 1) & 3));
            vread[vt] = *(const half8*)&Vl[pos << 4];
        }
        #pragma unroll
        for (int sub = 0; sub < 2; ++sub) {
            bool dmask = (t == dt) && (sub == (w & 1));
            if ((t == dt) && !(w & 1) && sub == 1) break;   // fully above diag
            int toff = sub << 4;
            // ---- QK^T from LDS (16x16x32, 2 chains) ----
            f32x4 sc0 = {0.f,0.f,0.f,0.f}, sc1 = {0.f,0.f,0.f,0.f};
            const char* kbase = &Kl[(toff + c) * 512];
            __builtin_amdgcn_s_setprio(1);
            #pragma unroll
            for (int kk = 0; kk < 8; kk += 2) {
                short8 a0 = *(const short8*)&kbase[(((kk * 4 + g)       ^ (c & 7)) << 4)];
                short8 a1 = *(const short8*)&kbase[((((kk + 1) * 4 + g) ^ (c & 7)) << 4)];
                sc0 = __builtin_amdgcn_mfma_f32_16x16x32_bf16(a0, qf[kk], sc0, 0, 0, 0);
                sc1 = __builtin_amdgcn_mfma_f32_16x16x32_bf16(a1, qf[kk + 1], sc1, 0, 0, 0);
            }
            __builtin_amdgcn_s_setprio(0);
            // ---- scale + diagonal mask ----
            float sv[4];
            #pragma unroll
            for (int r = 0; r < 4; ++r) sv[r] = (sc0[r] + sc1[r]) * 0.0625f;
            if (dmask) {
                #pragma unroll
                for (int r = 0; r < 4; ++r)
                    if (4 * g + r > c) sv[r] = -1e30f;
            }
            // ---- softmax: shuffle-free fast path ----
            float tm = fmaxf(fmaxf(sv[0], sv[1]), fmaxf(sv[2], sv[3]));
            if (!__all((int)(tm <= m + 8.f))) {          // rare slow path
                float tr = fmaxf(tm, __shfl_xor(tm, 16));
                tr = fmaxf(tr, __shfl_xor(tr, 32));
                float mnew = fmaxf(m, tr);
                float alpha = __expf(m - mnew);
                m = mnew;
                lsum *= alpha;
                #pragma unroll
                for (int i = 0; i < 16; ++i) acc[i] *= alpha;
            }
            float p[4];
            #pragma unroll
            for (int r = 0; r < 4; ++r) { p[r] = __expf(sv[r] - m); lsum += p[r]; }
            half4 pb;
            #pragma unroll
            for (int r = 0; r < 4; ++r) pb[r] = (_Float16)p[r];
            // ---- PV (16x16x16 f16) ----
            __builtin_amdgcn_s_setprio(1);
            #pragma unroll
            for (int vt = 0; vt < 16; ++vt) {
                half4 vf;
                #pragma unroll
                for (int jj = 0; jj < 4; ++jj) vf[jj] = vread[vt][sub * 4 + jj];
                acc[vt] = __builtin_amdgcn_mfma_f32_16x16x16f16(vf, pb, acc[vt], 0, 0, 0);
            }
            __builtin_amdgcn_s_setprio(0);
        }
    }

    // ---- epilogue: row-sum of lsum (only softmax shuffles), write ----
    lsum += __shfl_xor(lsum, 16);
    lsum += __shfl_xor(lsum, 32);
    float rl = 1.f / lsum;
    #pragma unroll
    for (int vt = 0; vt < 16; ++vt) {
        #pragma unroll
        for (int r = 0; r < 4; ++r)
            out[(((b << 8) + vt * 16 + 4 * g + r) << 10) + s0 + c] = acc[vt][r] * rl;
    }
}

// ---------- launcher ----------
extern "C" void kernel_launch(void* const* d_in, const int* in_sizes, int n_in,
                              void* d_out, int out_size, void* d_ws, size_t ws_size,
                              hipStream_t stream) {
    const float* x  = (const float*)d_in[0];
    const float* wq = (const float*)d_in[1];
    const float* bq = (const float*)d_in[2];
    const float* wk = (const float*)d_in[3];
    const float* bk = (const float*)d_in[4];
    const float* wv = (const float*)d_in[5];
    const float* bv = (const float*)d_in[6];
    float* out = (float*)d_out;

    char* ws = (char*)d_ws;
    unsigned short* Wb = (unsigned short*)ws;                       // 393,216 B
    unsigned short* X0 = (unsigned short*)(ws + 393216);            // 16,777,216 B
    unsigned short* Qb = (unsigned short*)(ws + 393216 + 16777216);
    unsigned short* Kb = (unsigned short*)(ws + 393216 + 2 * 16777216);
    _Float16*       Vb = (_Float16*)     (ws + 393216 + 3 * 16777216);

    wconv_kernel<<<768, 256, 0, stream>>>(wq, wk, wv, Wb);
    build_x0_kernel<<<dim3(32, 8, 32), 256, 0, stream>>>(x, X0);
    proj_kernel<<<dim3(16, 4, 96), 256, 0, stream>>>(X0, Wb, bq, bk, bv, Qb, Kb, Vb);
    attn_kernel<<<512, 256, 0, stream>>>(Qb, Kb, Vb, out);
}

// Round 14
// 111.947 us; speedup vs baseline: 1.3540x; 1.0454x over previous
//
#include <hip/hip_runtime.h>
#include <cstdint>

typedef float  f32x4  __attribute__((ext_vector_type(4)));
typedef short  short8 __attribute__((ext_vector_type(8)));
typedef _Float16 half4 __attribute__((ext_vector_type(4)));
typedef _Float16 half8 __attribute__((ext_vector_type(8)));

// ---------- helpers ----------
__device__ __forceinline__ unsigned short f2bf(float f) {
    unsigned u = __builtin_bit_cast(unsigned, f);
    u += 0x7FFFu + ((u >> 16) & 1u);   // RNE
    return (unsigned short)(u >> 16);
}

// ---------- kernel 1: weights fp32 -> bf16 (3 x 256 x 256) ----------
__global__ void wconv_kernel(const float* __restrict__ wq,
                             const float* __restrict__ wk,
                             const float* __restrict__ wv,
                             unsigned short* __restrict__ Wb) {
    int p = blockIdx.x >> 8;                       // 0..2
    int i = ((blockIdx.x & 255) << 8) + threadIdx.x; // 0..65535
    const float* src = (p == 0) ? wq : ((p == 1) ? wk : wv);
    Wb[(p << 16) + i] = f2bf(src[i]);
}

// ---------- kernel 2: build X0 [B][S][256] bf16 ----------
__global__ void build_x0_kernel(const float* __restrict__ x,
                                unsigned short* __restrict__ X0) {
    __shared__ float tile[32][33];
    int b  = blockIdx.z;
    int ct = blockIdx.y;     // 0..7  (32 channels each)
    int st = blockIdx.x;     // 0..31 (32 s each)
    int tid = threadIdx.x;
    int lo = tid & 31, hi = tid >> 5;   // 8 rows per pass

    if (ct < 7) {
        #pragma unroll
        for (int r = 0; r < 4; ++r) {
            int c = hi + 8 * r;
            tile[c][lo] = x[((b * 224 + ct * 32 + c) << 10) + st * 32 + lo];
        }
        __syncthreads();
        #pragma unroll
        for (int r = 0; r < 4; ++r) {
            int s_loc = hi + 8 * r;
            X0[(((b << 10) + st * 32 + s_loc) << 8) + ct * 32 + lo] = f2bf(tile[lo][s_loc]);
        }
    } else {
        #pragma unroll
        for (int r = 0; r < 4; ++r) {
            int s_loc = hi + 8 * r;
            int s = st * 32 + s_loc;
            int h = s >> 5, w = s & 31;
            int ch = lo;  // 0..31 -> pe channel
            int i = (ch < 16) ? (ch * 32 + h) : ((ch - 16) * 32 + w);
            int l = i >> 4, e = i & 15;
            float val = 0.f;
            if (l > 0) {
                float ang = (float)l * powf(10000.f, -(float)(e >> 1) * 0.125f);
                val = (e & 1) ? cosf(ang) : sinf(ang);
            }
            X0[(((b << 10) + s) << 8) + 224 + ch] = f2bf(val);
        }
    }
}

// ---------- kernel 3: QKV projection, glds-staged, 32x32 wave tiles ----------
// Block = (64-s tile, 64-o tile, proj*32+b). 4 waves = (wr,wc) each 32s x 32o
// (2x2 16x16 acc) -> block LDS reads 128 b128 for 128 MFMAs (was 544).
// X/W staged via global_load_lds with pre-swizzled source (attn-K pattern).
// V global layout (consumed by attn): per (b, v, 32-t tile) 32 f16 stored
// as slot = g*8 + hi*4 + j  where t_in_tile = hi*16 + 4g + j.
__global__ __launch_bounds__(256) void proj_kernel(
        const unsigned short* __restrict__ X0,
        const unsigned short* __restrict__ Wb,
        const float* __restrict__ bq, const float* __restrict__ bk,
        const float* __restrict__ bv,
        unsigned short* __restrict__ Q, unsigned short* __restrict__ K,
        _Float16* __restrict__ V) {
    __shared__ __align__(16) char Xlds[32768];   // 64 s-rows x 512B
    __shared__ __align__(16) char Wlds[32768];   // 64 o-rows x 512B

    int pb = blockIdx.z; int proj = pb >> 5; int b = pb & 31;
    int tid = threadIdx.x; int w = tid >> 6; int l = tid & 63;
    int g = l >> 4, c = l & 15;
    int wr = w >> 1, wc = w & 1;
    int sb = blockIdx.x * 64;           // s-tile base
    int o0 = blockIdx.y * 64;           // o-tile base
    const unsigned short* Wp = Wb + (proj << 16);
    const float* bias = (proj == 0) ? bq : ((proj == 1) ? bk : bv);

    // ---- stage X tile: 2048 chunks via global_load_lds, swizzled source ----
    const unsigned short* Xg = &X0[((b << 10) + sb) << 8];
    #pragma unroll
    for (int p = 0; p < 8; ++p) {
        int ch = p * 256 + tid;
        int row = ch >> 5;
        int cl = (ch & 31) ^ (row & 7);
        __builtin_amdgcn_global_load_lds(
            (const unsigned int*)&Xg[(row << 8) + cl * 8],
            (unsigned int*)(Xlds + ((p << 8) + (w << 6)) * 16), 16, 0, 0);
    }
    // ---- stage W tile: 2048 chunks ----
    const unsigned short* Wg = &Wp[o0 << 8];
    #pragma unroll
    for (int p = 0; p < 8; ++p) {
        int ch = p * 256 + tid;
        int row = ch >> 5;
        int cl = (ch & 31) ^ (row & 7);
        __builtin_amdgcn_global_load_lds(
            (const unsigned int*)&Wg[(row << 8) + cl * 8],
            (unsigned int*)(Wlds + ((p << 8) + (w << 6)) * 16), 16, 0, 0);
    }
    asm volatile("s_waitcnt vmcnt(0)\n\ts_barrier" ::: "memory");

    // ---- compute: 2x2 16x16 tiles per wave ----
    f32x4 acc[2][2];
    #pragma unroll
    for (int i = 0; i < 2; ++i)
        #pragma unroll
        for (int j = 0; j < 2; ++j) acc[i][j] = (f32x4){0.f, 0.f, 0.f, 0.f};

    const char* abase0 = &Xlds[(wr * 32 + c) * 512];
    const char* abase1 = &Xlds[(wr * 32 + 16 + c) * 512];
    const char* bbase0 = &Wlds[(wc * 32 + c) * 512];
    const char* bbase1 = &Wlds[(wc * 32 + 16 + c) * 512];

    __builtin_amdgcn_s_setprio(1);
    #pragma unroll
    for (int kk = 0; kk < 8; ++kk) {
        int co = ((kk * 4 + g) ^ (c & 7)) << 4;
        short8 a0 = *(const short8*)&abase0[co];
        short8 a1 = *(const short8*)&abase1[co];
        short8 b0 = *(const short8*)&bbase0[co];
        short8 b1 = *(const short8*)&bbase1[co];
        acc[0][0] = __builtin_amdgcn_mfma_f32_16x16x32_bf16(a0, b0, acc[0][0], 0, 0, 0);
        acc[0][1] = __builtin_amdgcn_mfma_f32_16x16x32_bf16(a0, b1, acc[0][1], 0, 0, 0);
        acc[1][0] = __builtin_amdgcn_mfma_f32_16x16x32_bf16(a1, b0, acc[1][0], 0, 0, 0);
        acc[1][1] = __builtin_amdgcn_mfma_f32_16x16x32_bf16(a1, b1, acc[1][1], 0, 0, 0);
    }
    __builtin_amdgcn_s_setprio(0);

    // ---- epilogue ----
    #pragma unroll
    for (int j = 0; j < 2; ++j) {
        int o = o0 + wc * 32 + j * 16 + c;
        float bb = bias[o];
        #pragma unroll
        for (int i = 0; i < 2; ++i) {
            int sgb = sb + wr * 32 + i * 16;      // 16-aligned s-group base
            if (proj < 2) {
                unsigned short* dst = (proj == 0) ? Q : K;
                #pragma unroll
                for (int r = 0; r < 4; ++r) {
                    float v = fmaxf(acc[i][j][r] + bb, 0.f);
                    int s = sgb + 4 * g + r;
                    dst[(((b << 10) + s) << 8) + o] = f2bf(v);
                }
            } else {
                half4 hv;
                #pragma unroll
                for (int r = 0; r < 4; ++r)
                    hv[r] = (_Float16)fmaxf(acc[i][j][r] + bb, 0.f);
                int hi = (sgb >> 4) & 1;
                *(half4*)&V[(((b << 8) + o) << 10) + ((sgb >> 5) << 5)
                            + (g << 3) + (hi << 2)] = hv;
            }
        }
    }
}

// ---------- kernel 4: causal attention (R13, unchanged) ----------
__global__ __launch_bounds__(256, 2) void attn_kernel(
        const unsigned short* __restrict__ Q,
        const unsigned short* __restrict__ K,
        const _Float16* __restrict__ V,
        float* __restrict__ out) {
    __shared__ __align__(16) char Klds[2][16384];   // 32 t-rows x 512B
    __shared__ __align__(16) char Vlds[2][16384];   // 1024 chunks x 16B

    int bid = blockIdx.x;
    int xcd  = bid & 7;
    int qv   = (bid >> 3) & 7;
    int bhi  = (bid >> 6) & 3;
    int hf   = bid >> 8;
    int b  = (bhi << 3) | xcd;
    int qt = hf ? qv : (15 - qv);       // 0..15, 64-row q-tile

    int tid = threadIdx.x; int w = tid >> 6; int l = tid & 63;
    int g = l >> 4, c = l & 15;
    int s0 = (qt << 6) + (w << 4);      // this wave's 16 q-rows

    // ---- Q fragments ----
    short8 qf[8];
    #pragma unroll
    for (int kk = 0; kk < 8; ++kk)
        qf[kk] = *(const short8*)&Q[(((b << 10) + s0 + c) << 8) + kk * 32 + g * 8];

    float m = -1e30f, lsum = 0.f;       // lsum: per-lane partial
    f32x4 acc[16];
    #pragma unroll
    for (int i = 0; i < 16; ++i) acc[i] = (f32x4){0.f, 0.f, 0.f, 0.f};

    const unsigned short* Kb_ = &K[(size_t)b << 18];
    const _Float16*       Vb_ = &V[(size_t)b << 18];

    int nt = 2 * qt + 2;                // 32-wide t-tiles
    int dt = 2 * qt + (w >> 1);         // this wave's diagonal t-tile

    auto stage = [&](int t, int bufi) {
        int t0 = t << 5;
        #pragma unroll
        for (int j = 0; j < 4; ++j) {
            int ch = (j << 8) + tid;            // 0..1023
            int trow = ch >> 5;
            int cl = (ch & 31) ^ (trow & 7);
            __builtin_amdgcn_global_load_lds(
                (const unsigned int*)&Kb_[((t0 + trow) << 8) + cl * 8],
                (unsigned int*)(Klds[bufi] + ((j << 8) + (w << 6)) * 16), 16, 0, 0);
        }
        #pragma unroll
        for (int j = 0; j < 4; ++j) {
            int ch = (j << 8) + tid;            // 0..1023
            int v = ch >> 2;
            int gq = (ch & 3) ^ ((v >> 1) & 3);
            __builtin_amdgcn_global_load_lds(
                (const unsigned int*)&Vb_[(v << 10) + (t << 5) + gq * 8],
                (unsigned int*)(Vlds[bufi] + ((j << 8) + (w << 6)) * 16), 16, 0, 0);
        }
    };

    stage(0, 0);

    for (int t = 0; t < nt; ++t) {
        asm volatile("s_waitcnt vmcnt(0)\n\ts_barrier" ::: "memory");
        if (t + 1 < nt) stage(t + 1, (t + 1) & 1);   // overlap with compute(t)
        if (t > dt) continue;                        // done; keep barrier cadence

        const char* Kl = Klds[t & 1];
        const char* Vl = Vlds[t & 1];
        // ---- V fragments: one conflict-free b128 per vt (both subs) ----
        half8 vread[16];
        #pragma unroll
        for (int vt = 0; vt < 16; ++vt) {
            int pos = (vt << 6) + (c << 2) + (g ^ ((c >> 1) & 3));
            vread[vt] = *(const half8*)&Vl[pos << 4];
        }
        #pragma unroll
        for (int sub = 0; sub < 2; ++sub) {
            bool dmask = (t == dt) && (sub == (w & 1));
            if ((t == dt) && !(w & 1) && sub == 1) break;   // fully above diag
            int toff = sub << 4;
            // ---- QK^T from LDS (16x16x32, 2 chains) ----
            f32x4 sc0 = {0.f,0.f,0.f,0.f}, sc1 = {0.f,0.f,0.f,0.f};
            const char* kbase = &Kl[(toff + c) * 512];
            __builtin_amdgcn_s_setprio(1);
            #pragma unroll
            for (int kk = 0; kk < 8; kk += 2) {
                short8 a0 = *(const short8*)&kbase[(((kk * 4 + g)       ^ (c & 7)) << 4)];
                short8 a1 = *(const short8*)&kbase[((((kk + 1) * 4 + g) ^ (c & 7)) << 4)];
                sc0 = __builtin_amdgcn_mfma_f32_16x16x32_bf16(a0, qf[kk], sc0, 0, 0, 0);
                sc1 = __builtin_amdgcn_mfma_f32_16x16x32_bf16(a1, qf[kk + 1], sc1, 0, 0, 0);
            }
            __builtin_amdgcn_s_setprio(0);
            // ---- scale + diagonal mask ----
            float sv[4];
            #pragma unroll
            for (int r = 0; r < 4; ++r) sv[r] = (sc0[r] + sc1[r]) * 0.0625f;
            if (dmask) {
                #pragma unroll
                for (int r = 0; r < 4; ++r)
                    if (4 * g + r > c) sv[r] = -1e30f;
            }
            // ---- softmax: shuffle-free fast path ----
            float tm = fmaxf(fmaxf(sv[0], sv[1]), fmaxf(sv[2], sv[3]));
            if (!__all((int)(tm <= m + 8.f))) {          // rare slow path
                float tr = fmaxf(tm, __shfl_xor(tm, 16));
                tr = fmaxf(tr, __shfl_xor(tr, 32));
                float mnew = fmaxf(m, tr);
                float alpha = __expf(m - mnew);
                m = mnew;
                lsum *= alpha;
                #pragma unroll
                for (int i = 0; i < 16; ++i) acc[i] *= alpha;
            }
            float p[4];
            #pragma unroll
            for (int r = 0; r < 4; ++r) { p[r] = __expf(sv[r] - m); lsum += p[r]; }
            half4 pb;
            #pragma unroll
            for (int r = 0; r < 4; ++r) pb[r] = (_Float16)p[r];
            // ---- PV (16x16x16 f16) ----
            __builtin_amdgcn_s_setprio(1);
            #pragma unroll
            for (int vt = 0; vt < 16; ++vt) {
                half4 vf;
                #pragma unroll
                for (int jj = 0; jj < 4; ++jj) vf[jj] = vread[vt][sub * 4 + jj];
                acc[vt] = __builtin_amdgcn_mfma_f32_16x16x16f16(vf, pb, acc[vt], 0, 0, 0);
            }
            __builtin_amdgcn_s_setprio(0);
        }
    }

    // ---- epilogue: row-sum of lsum (only softmax shuffles), write ----
    lsum += __shfl_xor(lsum, 16);
    lsum += __shfl_xor(lsum, 32);
    float rl = 1.f / lsum;
    #pragma unroll
    for (int vt = 0; vt < 16; ++vt) {
        #pragma unroll
        for (int r = 0; r < 4; ++r)
            out[(((b << 8) + vt * 16 + 4 * g + r) << 10) + s0 + c] = acc[vt][r] * rl;
    }
}

// ---------- launcher ----------
extern "C" void kernel_launch(void* const* d_in, const int* in_sizes, int n_in,
                              void* d_out, int out_size, void* d_ws, size_t ws_size,
                              hipStream_t stream) {
    const float* x  = (const float*)d_in[0];
    const float* wq = (const float*)d_in[1];
    const float* bq = (const float*)d_in[2];
    const float* wk = (const float*)d_in[3];
    const float* bk = (const float*)d_in[4];
    const float* wv = (const float*)d_in[5];
    const float* bv = (const float*)d_in[6];
    float* out = (float*)d_out;

    char* ws = (char*)d_ws;
    unsigned short* Wb = (unsigned short*)ws;                       // 393,216 B
    unsigned short* X0 = (unsigned short*)(ws + 393216);            // 16,777,216 B
    unsigned short* Qb = (unsigned short*)(ws + 393216 + 16777216);
    unsigned short* Kb = (unsigned short*)(ws + 393216 + 2 * 16777216);
    _Float16*       Vb = (_Float16*)     (ws + 393216 + 3 * 16777216);

    wconv_kernel<<<768, 256, 0, stream>>>(wq, wk, wv, Wb);
    build_x0_kernel<<<dim3(32, 8, 32), 256, 0, stream>>>(x, X0);
    proj_kernel<<<dim3(16, 4, 96), 256, 0, stream>>>(X0, Wb, bq, bk, bv, Qb, Kb, Vb);
    attn_kernel<<<512, 256, 0, stream>>>(Qb, Kb, Vb, out);
}

// Round 15
// 103.374 us; speedup vs baseline: 1.4663x; 1.0829x over previous
//
#include <hip/hip_runtime.h>
#include <cstdint>

typedef float  f32x4  __attribute__((ext_vector_type(4)));
typedef short  short8 __attribute__((ext_vector_type(8)));
typedef _Float16 half4 __attribute__((ext_vector_type(4)));
typedef _Float16 half8 __attribute__((ext_vector_type(8)));

// ---------- helpers ----------
__device__ __forceinline__ unsigned short f2bf(float f) {
    unsigned u = __builtin_bit_cast(unsigned, f);
    u += 0x7FFFu + ((u >> 16) & 1u);   // RNE
    return (unsigned short)(u >> 16);
}

// ---------- kernel 1: weights fp32 -> bf16 (3 x 256 x 256) ----------
__global__ void wconv_kernel(const float* __restrict__ wq,
                             const float* __restrict__ wk,
                             const float* __restrict__ wv,
                             unsigned short* __restrict__ Wb) {
    int p = blockIdx.x >> 8;                       // 0..2
    int i = ((blockIdx.x & 255) << 8) + threadIdx.x; // 0..65535
    const float* src = (p == 0) ? wq : ((p == 1) ? wk : wv);
    Wb[(p << 16) + i] = f2bf(src[i]);
}

// ---------- kernel 2: fused X0-build + QKV projection ----------
// Grid (16 s-tiles, 32 b) x 256 threads; 2 blocks/CU.
// Phase 1: build X-tile [64s][256c] bf16 in swizzled LDS directly from x
//   (transpose via f32 scratch aliased on Wlds) + analytic pos-enc channels.
// Phase 2: A-frags hoisted to regs once; 12 steps (3 proj x 4 o-tiles):
//   glds-stage W tile -> vmcnt(0)+barrier -> 2x2 16x16 MFMA -> epilogue.
// V global layout (consumed by attn): per (b, v, 32-t tile) 32 f16 stored
// as slot = g*8 + hi*4 + j  where t_in_tile = hi*16 + 4g + j.
__global__ __launch_bounds__(256, 2) void fproj_kernel(
        const float* __restrict__ x,
        const unsigned short* __restrict__ Wb,
        const float* __restrict__ bq, const float* __restrict__ bk,
        const float* __restrict__ bv,
        unsigned short* __restrict__ Q, unsigned short* __restrict__ K,
        _Float16* __restrict__ V) {
    __shared__ __align__(16) char Xlds[32768];   // 64 s-rows x 512B (swz)
    __shared__ __align__(16) char Wlds[32768];   // 64 o-rows x 512B (swz)
    float* Tt = (float*)Wlds;                    // phase-1 scratch [224][33]

    int st = blockIdx.x;            // s-tile 0..15
    int b  = blockIdx.y;            // 0..31
    int sb = st << 6;
    int tid = threadIdx.x; int w = tid >> 6; int l = tid & 63;
    int g = l >> 4, c = l & 15;
    int wr = w >> 1, wc = w & 1;

    // ---- phase 1: build X tile ----
    #pragma unroll 1
    for (int sc = 0; sc < 2; ++sc) {
        if (sc) __syncthreads();             // protect Tt reuse
        // load x chunk: 224 c-rows x 32 s-cols (coalesced)
        #pragma unroll
        for (int r = 0; r < 28; ++r) {
            int idx = r * 256 + tid;         // 0..7167
            int cc = idx >> 5, lo = idx & 31;
            Tt[cc * 33 + lo] = x[((b * 224 + cc) << 10) + sb + (sc << 5) + lo];
        }
        __syncthreads();
        // emit transposed bf16 16B chunks (c 0..223)
        #pragma unroll
        for (int r = 0; r < 4; ++r) {
            int idx = r * 256 + tid;         // use idx < 896
            if (idx < 896) {
                int cc16 = idx >> 5;         // 0..27
                int sl = idx & 31;
                int s = (sc << 5) + sl;      // 0..63
                short8 v8;
                #pragma unroll
                for (int j = 0; j < 8; ++j)
                    v8[j] = (short)f2bf(Tt[(cc16 * 8 + j) * 33 + sl]);
                *(short8*)&Xlds[(s << 9) + ((cc16 ^ (s & 7)) << 4)] = v8;
            }
        }
        // pos-enc chunks (c 224..255)
        if (tid < 128) {
            int sl = tid >> 2;
            int cc16 = 28 + (tid & 3);
            int s = (sc << 5) + sl;
            int sg = sb + s;
            int h = sg >> 5, ww = sg & 31;
            short8 v8;
            #pragma unroll
            for (int j = 0; j < 8; ++j) {
                int ch = (cc16 - 28) * 8 + j;        // 0..31
                int i = (ch < 16) ? (ch * 32 + h) : ((ch - 16) * 32 + ww);
                int ll = i >> 4, e = i & 15;
                float val = 0.f;
                if (ll > 0) {
                    float ang = (float)ll * powf(10000.f, -(float)(e >> 1) * 0.125f);
                    val = (e & 1) ? cosf(ang) : sinf(ang);
                }
                v8[j] = (short)f2bf(val);
            }
            *(short8*)&Xlds[(s << 9) + ((cc16 ^ (s & 7)) << 4)] = v8;
        }
    }
    __syncthreads();      // Xlds complete; Tt (Wlds) free

    // ---- hoist A fragments (wave's 32 s-rows) into registers ----
    short8 af[2][8];
    #pragma unroll
    for (int i = 0; i < 2; ++i) {
        const char* ab = &Xlds[(wr * 32 + i * 16 + c) << 9];
        #pragma unroll
        for (int kk = 0; kk < 8; ++kk)
            af[i][kk] = *(const short8*)&ab[((kk * 4 + g) ^ (c & 7)) << 4];
    }

    // ---- phase 2: 12 steps ----
    #pragma unroll 1
    for (int pj = 0; pj < 3; ++pj) {
        const float* bias = (pj == 0) ? bq : ((pj == 1) ? bk : bv);
        #pragma unroll 1
        for (int ot = 0; ot < 4; ++ot) {
            // stage W tile (64 o-rows x 512B), swizzled source
            const unsigned short* Wg = Wb + (pj << 16) + (ot << 14);
            #pragma unroll
            for (int p = 0; p < 8; ++p) {
                int ch = p * 256 + tid;
                int row = ch >> 5;
                int cl = (ch & 31) ^ (row & 7);
                __builtin_amdgcn_global_load_lds(
                    (const unsigned int*)&Wg[(row << 8) + cl * 8],
                    (unsigned int*)(Wlds + ((p << 8) + (w << 6)) * 16), 16, 0, 0);
            }
            asm volatile("s_waitcnt vmcnt(0)\n\ts_barrier" ::: "memory");

            f32x4 acc[2][2];
            #pragma unroll
            for (int i = 0; i < 2; ++i)
                #pragma unroll
                for (int j = 0; j < 2; ++j) acc[i][j] = (f32x4){0.f, 0.f, 0.f, 0.f};

            const char* bb0 = &Wlds[(wc * 32 + c) << 9];
            const char* bb1 = &Wlds[(wc * 32 + 16 + c) << 9];
            __builtin_amdgcn_s_setprio(1);
            #pragma unroll
            for (int kk = 0; kk < 8; ++kk) {
                int co = ((kk * 4 + g) ^ (c & 7)) << 4;
                short8 b0 = *(const short8*)&bb0[co];
                short8 b1 = *(const short8*)&bb1[co];
                acc[0][0] = __builtin_amdgcn_mfma_f32_16x16x32_bf16(af[0][kk], b0, acc[0][0], 0, 0, 0);
                acc[0][1] = __builtin_amdgcn_mfma_f32_16x16x32_bf16(af[0][kk], b1, acc[0][1], 0, 0, 0);
                acc[1][0] = __builtin_amdgcn_mfma_f32_16x16x32_bf16(af[1][kk], b0, acc[1][0], 0, 0, 0);
                acc[1][1] = __builtin_amdgcn_mfma_f32_16x16x32_bf16(af[1][kk], b1, acc[1][1], 0, 0, 0);
            }
            __builtin_amdgcn_s_setprio(0);

            // epilogue
            #pragma unroll
            for (int j = 0; j < 2; ++j) {
                int o = (ot << 6) + wc * 32 + j * 16 + c;
                float bbv = bias[o];
                #pragma unroll
                for (int i = 0; i < 2; ++i) {
                    int sgb = sb + wr * 32 + i * 16;
                    if (pj < 2) {
                        unsigned short* dst = (pj == 0) ? Q : K;
                        #pragma unroll
                        for (int r = 0; r < 4; ++r) {
                            float v = fmaxf(acc[i][j][r] + bbv, 0.f);
                            int s = sgb + 4 * g + r;
                            dst[(((b << 10) + s) << 8) + o] = f2bf(v);
                        }
                    } else {
                        half4 hv;
                        #pragma unroll
                        for (int r = 0; r < 4; ++r)
                            hv[r] = (_Float16)fmaxf(acc[i][j][r] + bbv, 0.f);
                        int hi = (sgb >> 4) & 1;
                        *(half4*)&V[(((b << 8) + o) << 10) + ((sgb >> 5) << 5)
                                    + (g << 3) + (hi << 2)] = hv;
                    }
                }
            }
            __syncthreads();    // all waves done reading Wlds before restage
        }
    }
}

// ---------- kernel 3: causal attention (R13/R14, unchanged) ----------
__global__ __launch_bounds__(256, 2) void attn_kernel(
        const unsigned short* __restrict__ Q,
        const unsigned short* __restrict__ K,
        const _Float16* __restrict__ V,
        float* __restrict__ out) {
    __shared__ __align__(16) char Klds[2][16384];   // 32 t-rows x 512B
    __shared__ __align__(16) char Vlds[2][16384];   // 1024 chunks x 16B

    int bid = blockIdx.x;
    int xcd  = bid & 7;
    int qv   = (bid >> 3) & 7;
    int bhi  = (bid >> 6) & 3;
    int hf   = bid >> 8;
    int b  = (bhi << 3) | xcd;
    int qt = hf ? qv : (15 - qv);       // 0..15, 64-row q-tile

    int tid = threadIdx.x; int w = tid >> 6; int l = tid & 63;
    int g = l >> 4, c = l & 15;
    int s0 = (qt << 6) + (w << 4);      // this wave's 16 q-rows

    // ---- Q fragments ----
    short8 qf[8];
    #pragma unroll
    for (int kk = 0; kk < 8; ++kk)
        qf[kk] = *(const short8*)&Q[(((b << 10) + s0 + c) << 8) + kk * 32 + g * 8];

    float m = -1e30f, lsum = 0.f;       // lsum: per-lane partial
    f32x4 acc[16];
    #pragma unroll
    for (int i = 0; i < 16; ++i) acc[i] = (f32x4){0.f, 0.f, 0.f, 0.f};

    const unsigned short* Kb_ = &K[(size_t)b << 18];
    const _Float16*       Vb_ = &V[(size_t)b << 18];

    int nt = 2 * qt + 2;                // 32-wide t-tiles
    int dt = 2 * qt + (w >> 1);         // this wave's diagonal t-tile

    auto stage = [&](int t, int bufi) {
        int t0 = t << 5;
        #pragma unroll
        for (int j = 0; j < 4; ++j) {
            int ch = (j << 8) + tid;            // 0..1023
            int trow = ch >> 5;
            int cl = (ch & 31) ^ (trow & 7);
            __builtin_amdgcn_global_load_lds(
                (const unsigned int*)&Kb_[((t0 + trow) << 8) + cl * 8],
                (unsigned int*)(Klds[bufi] + ((j << 8) + (w << 6)) * 16), 16, 0, 0);
        }
        #pragma unroll
        for (int j = 0; j < 4; ++j) {
            int ch = (j << 8) + tid;            // 0..1023
            int v = ch >> 2;
            int gq = (ch & 3) ^ ((v >> 1) & 3);
            __builtin_amdgcn_global_load_lds(
                (const unsigned int*)&Vb_[(v << 10) + (t << 5) + gq * 8],
                (unsigned int*)(Vlds[bufi] + ((j << 8) + (w << 6)) * 16), 16, 0, 0);
        }
    };

    stage(0, 0);

    for (int t = 0; t < nt; ++t) {
        asm volatile("s_waitcnt vmcnt(0)\n\ts_barrier" ::: "memory");
        if (t + 1 < nt) stage(t + 1, (t + 1) & 1);   // overlap with compute(t)
        if (t > dt) continue;                        // done; keep barrier cadence

        const char* Kl = Klds[t & 1];
        const char* Vl = Vlds[t & 1];
        // ---- V fragments: one conflict-free b128 per vt (both subs) ----
        half8 vread[16];
        #pragma unroll
        for (int vt = 0; vt < 16; ++vt) {
            int pos = (vt << 6) + (c << 2) + (g ^ ((c >> 1) & 3));
            vread[vt] = *(const half8*)&Vl[pos << 4];
        }
        #pragma unroll
        for (int sub = 0; sub < 2; ++sub) {
            bool dmask = (t == dt) && (sub == (w & 1));
            if ((t == dt) && !(w & 1) && sub == 1) break;   // fully above diag
            int toff = sub << 4;
            // ---- QK^T from LDS (16x16x32, 2 chains) ----
            f32x4 sc0 = {0.f,0.f,0.f,0.f}, sc1 = {0.f,0.f,0.f,0.f};
            const char* kbase = &Kl[(toff + c) * 512];
            __builtin_amdgcn_s_setprio(1);
            #pragma unroll
            for (int kk = 0; kk < 8; kk += 2) {
                short8 a0 = *(const short8*)&kbase[(((kk * 4 + g)       ^ (c & 7)) << 4)];
                short8 a1 = *(const short8*)&kbase[((((kk + 1) * 4 + g) ^ (c & 7)) << 4)];
                sc0 = __builtin_amdgcn_mfma_f32_16x16x32_bf16(a0, qf[kk], sc0, 0, 0, 0);
                sc1 = __builtin_amdgcn_mfma_f32_16x16x32_bf16(a1, qf[kk + 1], sc1, 0, 0, 0);
            }
            __builtin_amdgcn_s_setprio(0);
            // ---- scale + diagonal mask ----
            float sv[4];
            #pragma unroll
            for (int r = 0; r < 4; ++r) sv[r] = (sc0[r] + sc1[r]) * 0.0625f;
            if (dmask) {
                #pragma unroll
                for (int r = 0; r < 4; ++r)
                    if (4 * g + r > c) sv[r] = -1e30f;
            }
            // ---- softmax: shuffle-free fast path ----
            float tm = fmaxf(fmaxf(sv[0], sv[1]), fmaxf(sv[2], sv[3]));
            if (!__all((int)(tm <= m + 8.f))) {          // rare slow path
                float tr = fmaxf(tm, __shfl_xor(tm, 16));
                tr = fmaxf(tr, __shfl_xor(tr, 32));
                float mnew = fmaxf(m, tr);
                float alpha = __expf(m - mnew);
                m = mnew;
                lsum *= alpha;
                #pragma unroll
                for (int i = 0; i < 16; ++i) acc[i] *= alpha;
            }
            float p[4];
            #pragma unroll
            for (int r = 0; r < 4; ++r) { p[r] = __expf(sv[r] - m); lsum += p[r]; }
            half4 pb;
            #pragma unroll
            for (int r = 0; r < 4; ++r) pb[r] = (_Float16)p[r];
            // ---- PV (16x16x16 f16) ----
            __builtin_amdgcn_s_setprio(1);
            #pragma unroll
            for (int vt = 0; vt < 16; ++vt) {
                half4 vf;
                #pragma unroll
                for (int jj = 0; jj < 4; ++jj) vf[jj] = vread[vt][sub * 4 + jj];
                acc[vt] = __builtin_amdgcn_mfma_f32_16x16x16f16(vf, pb, acc[vt], 0, 0, 0);
            }
            __builtin_amdgcn_s_setprio(0);
        }
    }

    // ---- epilogue: row-sum of lsum (only softmax shuffles), write ----
    lsum += __shfl_xor(lsum, 16);
    lsum += __shfl_xor(lsum, 32);
    float rl = 1.f / lsum;
    #pragma unroll
    for (int vt = 0; vt < 16; ++vt) {
        #pragma unroll
        for (int r = 0; r < 4; ++r)
            out[(((b << 8) + vt * 16 + 4 * g + r) << 10) + s0 + c] = acc[vt][r] * rl;
    }
}

// ---------- launcher ----------
extern "C" void kernel_launch(void* const* d_in, const int* in_sizes, int n_in,
                              void* d_out, int out_size, void* d_ws, size_t ws_size,
                              hipStream_t stream) {
    const float* x  = (const float*)d_in[0];
    const float* wq = (const float*)d_in[1];
    const float* bq = (const float*)d_in[2];
    const float* wk = (const float*)d_in[3];
    const float* bk = (const float*)d_in[4];
    const float* wv = (const float*)d_in[5];
    const float* bv = (const float*)d_in[6];
    float* out = (float*)d_out;

    char* ws = (char*)d_ws;
    unsigned short* Wb = (unsigned short*)ws;                       // 393,216 B
    unsigned short* Qb = (unsigned short*)(ws + 393216);
    unsigned short* Kb = (unsigned short*)(ws + 393216 + 16777216);
    _Float16*       Vb = (_Float16*)     (ws + 393216 + 2 * 16777216);

    wconv_kernel<<<768, 256, 0, stream>>>(wq, wk, wv, Wb);
    fproj_kernel<<<dim3(16, 32), 256, 0, stream>>>(x, Wb, bq, bk, bv, Qb, Kb, Vb);
    attn_kernel<<<512, 256, 0, stream>>>(Qb, Kb, Vb, out);
}